// Round 2
// 324.961 us; speedup vs baseline: 1.2039x; 1.2039x over previous
//
#include <hip/hip_runtime.h>
#include <math.h>

#define MAXDEG 20
#define NM 21               // m = 0..20
#define RANK 256
#define PPB 12              // points per block
#define NSLOT (2*PPB)       // 24 (point,dir) table slots
#define TSTRIDE 233         // words per Legendre slot: 231 used, odd-ish (233%32=9) for write spread
#define HDRS 65             // header stride (odd -> no bank conflicts on pd-parallel reads)

// Storage layout inside a Legendre slot (231 used words of TSTRIDE):
//   packed columns by m: base(m) = 21*m - m*(m-1)/2, entry (l,m) at base(m) + (l-m).
//   Values are Pbar_{l,m} with sqrt(2) (m>=1) and Condon-Shortley phase folded in.
//   The cos(m phi)/sin(m phi) factor lives in the header and is applied at gather time:
//     Y_{l,+m} = tab[base(m)+(l-m)] * hdr[m]      (hdr[0]=1 covers m=0)
//     Y_{l,-m} = tab[base(m)+(l-m)] * hdr[21+m]
// Header per (p,d): [0..20]=cos(m phi) [21..41]=sin(m phi) [42..62]=Pmm seeds [63]=x

__device__ __forceinline__ void remap2(int k, int& pi, int& ti) {
  // flax index k = l*(l+1)+m  ->  (Legendre index, trig index)
  int l = (int)sqrtf((float)k);
  if (l*l > k) --l;
  if ((l+1)*(l+1) <= k) ++l;
  int m = k - l*(l+1);
  int am = m < 0 ? -m : m;
  pi = 21*am - (am*(am-1))/2 + (l - am);
  ti = (m == 0) ? 0 : (m > 0 ? am : 21 + am);
}

__global__ __launch_bounds__(256, 5)
void sh_fused(const float* __restrict__ coords,
              const int* __restrict__ rand_i,
              const int* __restrict__ rand_j,
              float* __restrict__ out, int N) {
  __shared__ float2 s_ab[231];              // normalized-recurrence coeffs (a,b) per tri(l,m)
  __shared__ float  s_hdr[NSLOT * HDRS];    // per (p,d) header
  __shared__ float  s_tab[NSLOT * TSTRIDE]; // per (p,d) packed Legendre table

  const int t  = threadIdx.x;
  const int n0 = blockIdx.x * PPB;

  // ---- remap gather indices (once, registers) ----
  int rip, rit, rjp, rjt;
  remap2(rand_i[t], rip, rit);
  remap2(rand_j[t], rjp, rjt);

  // ---- phase 0a: coefficient table. tri index t -> (l,m) ----
  if (t < 231) {
    int l = (int)((sqrtf(8.0f*(float)t + 1.0f) - 1.0f) * 0.5f);
    if (l*(l+1)/2 > t) --l;
    if ((l+1)*(l+2)/2 <= t) ++l;
    int m = t - l*(l+1)/2;
    float a = 0.f, b = 0.f;
    if (l >= m + 2) {
      float l2 = (float)(l*l), m2 = (float)(m*m);
      float inv = 1.0f / (l2 - m2);
      a = sqrtf((4.f*l2 - 1.f) * inv);
      b = sqrtf((2.f*(float)l + 1.f) * ((float)((l-1)*(l-1)) - m2)
                / (2.f*(float)l - 3.f) * inv);
    }
    s_ab[t] = make_float2(a, b);
  }

  // ---- phase 0b: per-(point,dir) header ----
  if (t < NSLOT) {
    int p = t >> 1, d = t & 1;
    int n = n0 + p; if (n >= N) n = N - 1;
    const float* c = coords + (size_t)n * 6 + d * 3;
    float cx = c[0], cy = c[1], cz = c[2];
    float r2 = cx*cx + cy*cy + cz*cz;
    float x = cz * rsqrtf(r2);                 // cos(inclination)
    x = fminf(1.f, fmaxf(-1.f, x));
    float s = sqrtf(fmaxf(0.f, 1.f - x*x));    // sin(inclination) >= 0
    float rho2 = cx*cx + cy*cy;
    float cphi, sphi;
    if (rho2 > 0.f) { float ir = rsqrtf(rho2); cphi = cx*ir; sphi = cy*ir; }
    else            { cphi = 1.f; sphi = 0.f; }   // atan2(0,0)=0 convention
    float* h = s_hdr + t * HDRS;
    float cm = 1.f, sm = 0.f;
    float pmm = 0.28209479177387814f;          // sqrt(1/(4*pi)) = Pbar_00
    h[0] = 1.f; h[21] = 0.f; h[42] = pmm; h[63] = x;
    for (int m = 1; m <= MAXDEG; ++m) {
      float cn = cm*cphi - sm*sphi;            // incremental rotation -> cos/sin(m phi)
      float sn = sm*cphi + cm*sphi;
      cm = cn; sm = sn;
      float df = -sqrtf((2.f*(float)m + 1.f) / (2.f*(float)m));  // CS phase
      if (m == 1) df *= 1.41421356237309515f;  // fold sqrt(2) for all m>=1
      pmm = df * s * pmm;
      h[m] = cm; h[21+m] = sm; h[42+m] = pmm;
    }
  }
  __syncthreads();

  // ---- phase 1: fill Legendre tables (no trig multiply, branch-free across m) ----
  for (int task = t; task < NM * NSLOT; task += 256) {
    int m  = task / NSLOT;          // major = m (sorted -> low trip-count divergence)
    int pd = task - m * NSLOT;
    const float* h = s_hdr + pd * HDRS;
    float x  = h[63];
    float p1 = h[42+m];
    float* col = s_tab + pd * TSTRIDE + (21*m - (m*(m-1))/2);
    col[0] = p1;                               // l = m
    if (m < MAXDEG) {
      float p2 = p1;
      float pc = sqrtf(2.f*(float)m + 3.f) * x * p1;   // l = m+1
      col[1] = pc;
      int ti = (m+2)*(m+3)/2 + m;              // tri(m+2, m)
      for (int l = m+2; l <= MAXDEG; ++l) {
        float2 ab = s_ab[ti];
        float pn = ab.x * (x * pc) - ab.y * p2;
        p2 = pc; pc = pn;
        col[l-m] = pn;
        ti += l + 1;
      }
    }
  }
  __syncthreads();

  // ---- phase 2: gathered products (Legendre * trig per side), coalesced store ----
  #pragma unroll
  for (int p = 0; p < PPB; ++p) {
    int n = n0 + p;
    if (n < N) {
      const float* sA = s_tab + (2*p)   * TSTRIDE;
      const float* hA = s_hdr + (2*p)   * HDRS;
      const float* sB = s_tab + (2*p+1) * TSTRIDE;
      const float* hB = s_hdr + (2*p+1) * HDRS;
      float v = (sA[rip] * hA[rit]) * (sB[rjp] * hB[rjt]);
      out[(size_t)n * RANK + t] = v;
    }
  }
}

extern "C" void kernel_launch(void* const* d_in, const int* in_sizes, int n_in,
                              void* d_out, int out_size, void* d_ws, size_t ws_size,
                              hipStream_t stream) {
  const float* coords = (const float*)d_in[0];
  const int*   rand_i = (const int*)d_in[1];
  const int*   rand_j = (const int*)d_in[2];
  float*       out    = (float*)d_out;
  const int N = in_sizes[0] / 6;
  const int grid = (N + PPB - 1) / PPB;
  sh_fused<<<grid, 256, 0, stream>>>(coords, rand_i, rand_j, out, N);
}